// Round 3
// baseline (235.156 us; speedup 1.0000x reference)
//
#include <hip/hip_runtime.h>
#include <hip/hip_cooperative_groups.h>
#include <math.h>

namespace cg = cooperative_groups;

#define QSCALE (0.2886751345948129f * 1.4426950408889634f)  // 1/sqrt(12) * log2(e)

#if __has_builtin(__builtin_amdgcn_exp2f)
#define EXP2F(x) __builtin_amdgcn_exp2f(x)
#else
#define EXP2F(x) exp2f(x)
#endif

typedef __attribute__((ext_vector_type(8))) _Float16 half8;
typedef __attribute__((ext_vector_type(4))) _Float16 half4_t;
typedef __attribute__((ext_vector_type(4))) float floatx4;

#define MFMA32F16(a, b, c) __builtin_amdgcn_mfma_f32_16x16x32_f16((a), (b), (c), 0, 0, 0)
#define MFMA16F16(a, b, c) __builtin_amdgcn_mfma_f32_16x16x16f16((a), (b), (c), 0, 0, 0)

static __device__ inline float bperm(float v, int addr_bytes) {
    return __int_as_float(__builtin_amdgcn_ds_bpermute(addr_bytes, __float_as_int(v)));
}

// ============================================================================
// Fused cooperative kernel: P0 prep -> grid.sync -> P1 QKV -> grid.sync -> P2
// attn. grid=512x256 (2 blocks/CU co-resident, 12 KB LDS, VGPR<<256).
// Math is bit-identical to the verified 3-kernel version; only the dispatch
// structure changed. grid.sync() provides the device-scope release/acquire
// the kernel boundaries used to provide (cross-XCD L2 visibility).
// ============================================================================
__global__ __launch_bounds__(256, 2)
void fused(const float* __restrict__ x, const int* __restrict__ mask,
           const float* __restrict__ Wq, const float* __restrict__ Wk,
           const float* __restrict__ Wv,
           _Float16* __restrict__ wfh, _Float16* __restrict__ wfl,
           int* __restrict__ dst, int* __restrict__ nvalid,
           float4* __restrict__ zbase,
           _Float16* __restrict__ qA, _Float16* __restrict__ qB,
           _Float16* __restrict__ kfp, _Float16* __restrict__ vtf,
           float* __restrict__ out)
{
    cg::grid_group grid = cg::this_grid();
    __shared__ __align__(16) float smem_f[3072];   // 12 KB, reused per phase
    const int b    = blockIdx.x;
    const int tid  = threadIdx.x;
    const int lane = tid & 63;
    const int w    = tid >> 6;
    const int m15  = lane & 15;
    const int q8   = lane >> 4;

    // ---------------- P0: prep (wswz | mask_scan | zero) ----------------
    if (b < 18) {
        int t = b * 256 + tid;
        if (t < 4608) {                    // 24 ks * 3 nt * 64 lanes
            int l2 = t & 63;
            int wt = (t >> 6) % 3;
            int ks = t / 192;
            const float* W = (wt == 0) ? Wq : (wt == 1) ? Wk : Wv;
            const float scale = (wt == 0) ? QSCALE : 1.0f;
            int col = l2 & 15;
            int qq  = l2 >> 4;
            half8 hi, lo;
            #pragma unroll
            for (int j = 0; j < 8; ++j) {
                int dim = ks * 32 + qq * 8 + j;
                float f = (col < 12) ? W[dim * 12 + col] * scale : 0.0f;
                _Float16 h = (_Float16)f;
                hi[j] = h;
                lo[j] = (_Float16)(f - (float)h);
            }
            size_t off = ((size_t)(ks * 3 + wt) * 64 + l2) * 8;
            *(half8*)(wfh + off) = hi;
            *(half8*)(wfl + off) = lo;
        }
    } else if (b < 26) {
        int* cnt = (int*)smem_f;
        const int bb = b - 18;
        const int* mb = mask + bb * 2048;
        int local[8]; int c = 0;
        #pragma unroll
        for (int i = 0; i < 8; ++i) { local[i] = (mb[tid * 8 + i] != 0); c += local[i]; }
        cnt[tid] = c;
        __syncthreads();
        for (int off = 1; off < 256; off <<= 1) {
            int u = cnt[tid];
            int add = (tid >= off) ? cnt[tid - off] : 0;
            __syncthreads();
            cnt[tid] = u + add;
            __syncthreads();
        }
        int run = (tid == 0) ? 0 : cnt[tid - 1];
        int* db = dst + bb * 2048;
        #pragma unroll
        for (int i = 0; i < 8; ++i) { db[tid * 8 + i] = local[i] ? run : -1; run += local[i]; }
        if (tid == 255) nvalid[bb] = cnt[255];
    } else {
        const float4 z = make_float4(0.f, 0.f, 0.f, 0.f);
        for (int i = (b - 26) * 256 + tid; i < 163840; i += 486 * 256) zbase[i] = z;
    }
    grid.sync();

    // ---------------- P1: QKV projection (2 row-groups per block) --------
    {
        float* cbuf = smem_f;
        const half8* WH = (const half8*)wfh;
        const half8* WL = (const half8*)wfl;
        for (int g = b; g < 1024; g += 512) {
            const int rowbase = g * 16;
            const float* xbase = x + (size_t)(rowbase + m15) * 768 + q8 * 8;

            float xv[6][8];
            #pragma unroll
            for (int s = 0; s < 6; ++s) {
                const int ks = w * 6 + s;
                *(float4*)(xv[s])     = *(const float4*)(xbase + ks * 32);
                *(float4*)(xv[s] + 4) = *(const float4*)(xbase + ks * 32 + 4);
            }

            floatx4 acc0 = {0.f, 0.f, 0.f, 0.f};
            floatx4 acc1 = acc0, acc2 = acc0;

            half8 bh[2][3], bl[2][3];
            {
                const int ks = w * 6;
                #pragma unroll
                for (int n = 0; n < 3; ++n) {
                    bh[0][n] = WH[(ks * 3 + n) * 64 + lane];
                    bl[0][n] = WL[(ks * 3 + n) * 64 + lane];
                }
            }

            #pragma unroll
            for (int s = 0; s < 6; ++s) {
                const int cur = s & 1, nxt = cur ^ 1;
                if (s < 5) {
                    const int ksn = w * 6 + s + 1;
                    #pragma unroll
                    for (int n = 0; n < 3; ++n) {
                        bh[nxt][n] = WH[(ksn * 3 + n) * 64 + lane];
                        bl[nxt][n] = WL[(ksn * 3 + n) * 64 + lane];
                    }
                }
                half8 ah, al;
                #pragma unroll
                for (int j = 0; j < 8; ++j) {
                    _Float16 h = (_Float16)xv[s][j];
                    ah[j] = h;
                    al[j] = (_Float16)(xv[s][j] - (float)h);
                }
                acc0 = MFMA32F16(ah, bh[cur][0], acc0);
                acc1 = MFMA32F16(ah, bh[cur][1], acc1);
                acc2 = MFMA32F16(ah, bh[cur][2], acc2);
                acc0 = MFMA32F16(al, bh[cur][0], acc0);
                acc1 = MFMA32F16(al, bh[cur][1], acc1);
                acc2 = MFMA32F16(al, bh[cur][2], acc2);
                acc0 = MFMA32F16(ah, bl[cur][0], acc0);
                acc1 = MFMA32F16(ah, bl[cur][1], acc1);
                acc2 = MFMA32F16(ah, bl[cur][2], acc2);
            }

            *(floatx4*)(cbuf + ((w * 3 + 0) * 64 + lane) * 4) = acc0;
            *(floatx4*)(cbuf + ((w * 3 + 1) * 64 + lane) * 4) = acc1;
            *(floatx4*)(cbuf + ((w * 3 + 2) * 64 + lane) * 4) = acc2;
            __syncthreads();
            if (w < 3) {
                floatx4 t0 = *(const floatx4*)(cbuf + ((0 * 3 + w) * 64 + lane) * 4);
                floatx4 t1 = *(const floatx4*)(cbuf + ((1 * 3 + w) * 64 + lane) * 4);
                floatx4 t2 = *(const floatx4*)(cbuf + ((2 * 3 + w) * 64 + lane) * 4);
                floatx4 t3 = *(const floatx4*)(cbuf + ((3 * 3 + w) * 64 + lane) * 4);
                floatx4 tot = t0 + t1 + t2 + t3;
                const int col = m15;
                const int r0  = q8 * 4;
                #pragma unroll
                for (int r = 0; r < 4; ++r) {
                    const int row = rowbase + r0 + r;
                    const float val = tot[r];
                    if (w == 0) {                  // Q -> qA (hi dup) + qB (lo)
                        if (col < 12) {
                            size_t fb = (size_t)g * 64;
                            size_t offL = (fb + (col >> 3) * 16 + (r0 + r)) * 8 + (col & 7);
                            size_t offH = (fb + (2 + (col >> 3)) * 16 + (r0 + r)) * 8 + (col & 7);
                            _Float16 h = (_Float16)val;
                            qA[offL] = h;
                            qA[offH] = h;
                            qB[offL] = (_Float16)(val - (float)h);
                        }
                    } else {
                        const int d = dst[row];
                        if (d >= 0) {
                            const int bb = row >> 11;
                            if (w == 1) {          // K -> packed hi|lo A-frag
                                if (col < 12) {
                                    size_t fb = ((size_t)(bb * 128 + (d >> 4))) * 64;
                                    size_t offH = (fb + (col >> 3) * 16 + (d & 15)) * 8 + (col & 7);
                                    size_t offL = (fb + (2 + (col >> 3)) * 16 + (d & 15)) * 8 + (col & 7);
                                    _Float16 h = (_Float16)val;
                                    kfp[offH] = h;
                                    kfp[offL] = (_Float16)(val - (float)h);
                                }
                            } else {               // V^T A-frag + ones row
                                if (col < 12) {
                                    size_t off = (((size_t)(bb * 128 + (d >> 4))) * 64
                                                  + ((d & 15) >> 2) * 16 + col) * 4 + (d & 3);
                                    vtf[off] = (_Float16)val;
                                } else if (col == 12) {
                                    size_t off = (((size_t)(bb * 128 + (d >> 4))) * 64
                                                  + ((d & 15) >> 2) * 16 + 12) * 4 + (d & 3);
                                    vtf[off] = (_Float16)1.0f;
                                }
                            }
                        }
                    }
                }
            }
            __syncthreads();
        }
    }
    grid.sync();

    // ---------------- P2: MFMA flash attention ----------------
    {
        float* cm = smem_f;                        // 512 floats
        floatx4* co = (floatx4*)(smem_f + 512);    // 512 floatx4
        const int bb = b & 7;                      // XCD-pinned batch
        const int gl = b >> 3;
        const int g0 = bb * 128 + gl * 2;

        const half8 qA0 = *(const half8*)(qA + ((size_t)g0 * 64 + lane) * 8);
        const half8 qB0 = *(const half8*)(qB + ((size_t)g0 * 64 + lane) * 8);
        const half8 qA1 = *(const half8*)(qA + ((size_t)(g0 + 1) * 64 + lane) * 8);
        const half8 qB1 = *(const half8*)(qB + ((size_t)(g0 + 1) * 64 + lane) * 8);

        const half8* KP = (const half8*)kfp + (size_t)bb * 128 * 64;
        const half4_t* VT = (const half4_t*)vtf + (size_t)bb * 128 * 64;

        const int nv = nvalid[bb];
        const int ntk = (nv + 15) >> 4;            // 16-key tiles (<=128)
        const int a16 = (lane ^ 16) << 2;
        const int a32 = (lane ^ 32) << 2;

        float m0 = -INFINITY, m1 = -INFINITY;
        floatx4 o0 = {0.f, 0.f, 0.f, 0.f};
        floatx4 o1 = o0;

        int t = w;
        half8 kp;
        half4_t va;
        if (t < ntk) {
            kp = KP[t * 64 + lane];
            va = VT[t * 64 + lane];
        }
        for (; t < ntk; t += 4) {
            half8 nkp; half4_t nva;
            if (t + 4 < ntk) {
                nkp = KP[(t + 4) * 64 + lane];
                nva = VT[(t + 4) * 64 + lane];
            }
            const floatx4 z = {0.f, 0.f, 0.f, 0.f};
            floatx4 s0a = MFMA32F16(kp, qA0, z);   // kh*qh + kl*qh
            floatx4 s0b = MFMA32F16(kp, qB0, z);   // kh*ql
            floatx4 s1a = MFMA32F16(kp, qA1, z);
            floatx4 s1b = MFMA32F16(kp, qB1, z);
            floatx4 s0 = s0a + s0b;
            floatx4 s1 = s1a + s1b;
            {
                float pm = fmaxf(fmaxf(s0.x, s0.y), fmaxf(s0.z, s0.w));
                pm = fmaxf(pm, bperm(pm, a16));
                pm = fmaxf(pm, bperm(pm, a32));
                half4_t pb;
                if (__all(pm <= m0)) {             // defer: mnew == m0 exactly
                    pb[0] = (_Float16)EXP2F(s0.x - m0);
                    pb[1] = (_Float16)EXP2F(s0.y - m0);
                    pb[2] = (_Float16)EXP2F(s0.z - m0);
                    pb[3] = (_Float16)EXP2F(s0.w - m0);
                } else {
                    float mnew = fmaxf(m0, pm);
                    float corr = EXP2F(m0 - mnew);
                    o0.x *= corr; o0.y *= corr; o0.z *= corr; o0.w *= corr;
                    pb[0] = (_Float16)EXP2F(s0.x - mnew);
                    pb[1] = (_Float16)EXP2F(s0.y - mnew);
                    pb[2] = (_Float16)EXP2F(s0.z - mnew);
                    pb[3] = (_Float16)EXP2F(s0.w - mnew);
                    m0 = mnew;
                }
                o0 = MFMA16F16(va, pb, o0);
            }
            {
                float pm = fmaxf(fmaxf(s1.x, s1.y), fmaxf(s1.z, s1.w));
                pm = fmaxf(pm, bperm(pm, a16));
                pm = fmaxf(pm, bperm(pm, a32));
                half4_t pb;
                if (__all(pm <= m1)) {
                    pb[0] = (_Float16)EXP2F(s1.x - m1);
                    pb[1] = (_Float16)EXP2F(s1.y - m1);
                    pb[2] = (_Float16)EXP2F(s1.z - m1);
                    pb[3] = (_Float16)EXP2F(s1.w - m1);
                } else {
                    float mnew = fmaxf(m1, pm);
                    float corr = EXP2F(m1 - mnew);
                    o1.x *= corr; o1.y *= corr; o1.z *= corr; o1.w *= corr;
                    pb[0] = (_Float16)EXP2F(s1.x - mnew);
                    pb[1] = (_Float16)EXP2F(s1.y - mnew);
                    pb[2] = (_Float16)EXP2F(s1.z - mnew);
                    pb[3] = (_Float16)EXP2F(s1.w - mnew);
                    m1 = mnew;
                }
                o1 = MFMA16F16(va, pb, o1);
            }
            kp = nkp; va = nva;
        }

        cm[(0 * 4 + w) * 64 + lane] = m0;
        cm[(1 * 4 + w) * 64 + lane] = m1;
        co[(0 * 4 + w) * 64 + lane] = o0;
        co[(1 * 4 + w) * 64 + lane] = o1;
        __syncthreads();
        if (w < 2) {
            const int gi = w;
            float gm = -INFINITY;
            #pragma unroll
            for (int w2 = 0; w2 < 4; ++w2) gm = fmaxf(gm, cm[(gi * 4 + w2) * 64 + lane]);
            floatx4 O = {0.f, 0.f, 0.f, 0.f};
            #pragma unroll
            for (int w2 = 0; w2 < 4; ++w2) {
                float f = EXP2F(cm[(gi * 4 + w2) * 64 + lane] - gm);
                floatx4 ow = co[(gi * 4 + w2) * 64 + lane];
                O.x += ow.x * f; O.y += ow.y * f; O.z += ow.z * f; O.w += ow.w * f;
            }
            float L = bperm(O.x, (48 + m15) << 2);   // l at C row 12
            float inv = 1.0f / L;
            if ((lane >> 4) < 3) {
                float4 ov = make_float4(O.x * inv, O.y * inv, O.z * inv, O.w * inv);
                *(float4*)(out + ((size_t)(g0 + gi) * 16 + m15) * 12 + (lane >> 4) * 4) = ov;
            }
        }
    }
}

// ======================= fallback 3-kernel path ============================
__global__ __launch_bounds__(256)
void prep(const float* __restrict__ Wq, const float* __restrict__ Wk,
          const float* __restrict__ Wv, const int* __restrict__ mask,
          _Float16* __restrict__ wfh, _Float16* __restrict__ wfl,
          int* __restrict__ dst, int* __restrict__ nvalid,
          float4* __restrict__ zbase)
{
    const int b = blockIdx.x;
    const int tid = threadIdx.x;
    if (b < 18) {
        int t = b * 256 + tid;
        if (t >= 4608) return;
        int lane = t & 63;
        int nt   = (t >> 6) % 3;
        int ks   = t / 192;
        const float* W = (nt == 0) ? Wq : (nt == 1) ? Wk : Wv;
        const float scale = (nt == 0) ? QSCALE : 1.0f;
        int col = lane & 15;
        int q8  = lane >> 4;
        half8 hi, lo;
        #pragma unroll
        for (int j = 0; j < 8; ++j) {
            int dim = ks * 32 + q8 * 8 + j;
            float f = (col < 12) ? W[dim * 12 + col] * scale : 0.0f;
            _Float16 h = (_Float16)f;
            hi[j] = h;
            lo[j] = (_Float16)(f - (float)h);
        }
        size_t off = ((size_t)(ks * 3 + nt) * 64 + lane) * 8;
        *(half8*)(wfh + off) = hi;
        *(half8*)(wfl + off) = lo;
    } else if (b < 26) {
        __shared__ int cnt[256];
        const int bb = b - 18;
        const int* mb = mask + bb * 2048;
        int local[8]; int c = 0;
        #pragma unroll
        for (int i = 0; i < 8; ++i) { local[i] = (mb[tid * 8 + i] != 0); c += local[i]; }
        cnt[tid] = c;
        __syncthreads();
        for (int off = 1; off < 256; off <<= 1) {
            int u = cnt[tid];
            int add = (tid >= off) ? cnt[tid - off] : 0;
            __syncthreads();
            cnt[tid] = u + add;
            __syncthreads();
        }
        int run = (tid == 0) ? 0 : cnt[tid - 1];
        int* db = dst + bb * 2048;
        #pragma unroll
        for (int i = 0; i < 8; ++i) { db[tid * 8 + i] = local[i] ? run : -1; run += local[i]; }
        if (tid == 255) nvalid[bb] = cnt[255];
    } else {
        const float4 z = make_float4(0.f, 0.f, 0.f, 0.f);
        for (int i = (b - 26) * 256 + tid; i < 163840; i += 38 * 256) zbase[i] = z;
    }
}

__global__ __launch_bounds__(256, 3)
void qkv_mfma(const float* __restrict__ x, const _Float16* __restrict__ wfh,
              const _Float16* __restrict__ wfl, const int* __restrict__ dst,
              _Float16* __restrict__ qA, _Float16* __restrict__ qB,
              _Float16* __restrict__ kfp, _Float16* __restrict__ vtf)
{
    __shared__ __align__(16) float cbuf[3072];
    const int tid  = threadIdx.x;
    const int lane = tid & 63;
    const int w    = tid >> 6;
    const int g    = blockIdx.x;
    const int rowbase = g * 16;
    const int m15 = lane & 15;
    const int q8  = lane >> 4;

    const float* xbase = x + (size_t)(rowbase + m15) * 768 + q8 * 8;
    const half8* WH = (const half8*)wfh;
    const half8* WL = (const half8*)wfl;

    float xv[6][8];
    #pragma unroll
    for (int s = 0; s < 6; ++s) {
        const int ks = w * 6 + s;
        *(float4*)(xv[s])     = *(const float4*)(xbase + ks * 32);
        *(float4*)(xv[s] + 4) = *(const float4*)(xbase + ks * 32 + 4);
    }

    floatx4 acc0 = {0.f, 0.f, 0.f, 0.f};
    floatx4 acc1 = acc0, acc2 = acc0;

    half8 bh[2][3], bl[2][3];
    {
        const int ks = w * 6;
        #pragma unroll
        for (int n = 0; n < 3; ++n) {
            bh[0][n] = WH[(ks * 3 + n) * 64 + lane];
            bl[0][n] = WL[(ks * 3 + n) * 64 + lane];
        }
    }

    #pragma unroll
    for (int s = 0; s < 6; ++s) {
        const int cur = s & 1, nxt = cur ^ 1;
        if (s < 5) {
            const int ksn = w * 6 + s + 1;
            #pragma unroll
            for (int n = 0; n < 3; ++n) {
                bh[nxt][n] = WH[(ksn * 3 + n) * 64 + lane];
                bl[nxt][n] = WL[(ksn * 3 + n) * 64 + lane];
            }
        }
        half8 ah, al;
        #pragma unroll
        for (int j = 0; j < 8; ++j) {
            _Float16 h = (_Float16)xv[s][j];
            ah[j] = h;
            al[j] = (_Float16)(xv[s][j] - (float)h);
        }
        acc0 = MFMA32F16(ah, bh[cur][0], acc0);
        acc1 = MFMA32F16(ah, bh[cur][1], acc1);
        acc2 = MFMA32F16(ah, bh[cur][2], acc2);
        acc0 = MFMA32F16(al, bh[cur][0], acc0);
        acc1 = MFMA32F16(al, bh[cur][1], acc1);
        acc2 = MFMA32F16(al, bh[cur][2], acc2);
        acc0 = MFMA32F16(ah, bl[cur][0], acc0);
        acc1 = MFMA32F16(ah, bl[cur][1], acc1);
        acc2 = MFMA32F16(ah, bl[cur][2], acc2);
    }

    *(floatx4*)(cbuf + ((w * 3 + 0) * 64 + lane) * 4) = acc0;
    *(floatx4*)(cbuf + ((w * 3 + 1) * 64 + lane) * 4) = acc1;
    *(floatx4*)(cbuf + ((w * 3 + 2) * 64 + lane) * 4) = acc2;
    __syncthreads();
    if (w < 3) {
        floatx4 t0 = *(const floatx4*)(cbuf + ((0 * 3 + w) * 64 + lane) * 4);
        floatx4 t1 = *(const floatx4*)(cbuf + ((1 * 3 + w) * 64 + lane) * 4);
        floatx4 t2 = *(const floatx4*)(cbuf + ((2 * 3 + w) * 64 + lane) * 4);
        floatx4 t3 = *(const floatx4*)(cbuf + ((3 * 3 + w) * 64 + lane) * 4);
        floatx4 tot = t0 + t1 + t2 + t3;
        const int col = m15;
        const int r0  = q8 * 4;
        #pragma unroll
        for (int r = 0; r < 4; ++r) {
            const int row = rowbase + r0 + r;
            const float val = tot[r];
            if (w == 0) {
                if (col < 12) {
                    size_t fb = (size_t)g * 64;
                    size_t offL = (fb + (col >> 3) * 16 + (r0 + r)) * 8 + (col & 7);
                    size_t offH = (fb + (2 + (col >> 3)) * 16 + (r0 + r)) * 8 + (col & 7);
                    _Float16 h = (_Float16)val;
                    qA[offL] = h;
                    qA[offH] = h;
                    qB[offL] = (_Float16)(val - (float)h);
                }
            } else {
                const int d = dst[row];
                if (d >= 0) {
                    const int bb = row >> 11;
                    if (w == 1) {
                        if (col < 12) {
                            size_t fb = ((size_t)(bb * 128 + (d >> 4))) * 64;
                            size_t offH = (fb + (col >> 3) * 16 + (d & 15)) * 8 + (col & 7);
                            size_t offL = (fb + (2 + (col >> 3)) * 16 + (d & 15)) * 8 + (col & 7);
                            _Float16 h = (_Float16)val;
                            kfp[offH] = h;
                            kfp[offL] = (_Float16)(val - (float)h);
                        }
                    } else {
                        if (col < 12) {
                            size_t off = (((size_t)(bb * 128 + (d >> 4))) * 64
                                          + ((d & 15) >> 2) * 16 + col) * 4 + (d & 3);
                            vtf[off] = (_Float16)val;
                        } else if (col == 12) {
                            size_t off = (((size_t)(bb * 128 + (d >> 4))) * 64
                                          + ((d & 15) >> 2) * 16 + 12) * 4 + (d & 3);
                            vtf[off] = (_Float16)1.0f;
                        }
                    }
                }
            }
        }
    }
}

__global__ __launch_bounds__(256)
void attn(const _Float16* __restrict__ qAf, const _Float16* __restrict__ qBf,
          const _Float16* __restrict__ kfp, const _Float16* __restrict__ vtf,
          const int* __restrict__ nvalid, float* __restrict__ out)
{
    __shared__ float cm[512];
    __shared__ __align__(16) floatx4 co[512];
    const int tid  = threadIdx.x;
    const int lane = tid & 63;
    const int w    = tid >> 6;
    const int bb   = blockIdx.x & 7;
    const int gl   = blockIdx.x >> 3;
    const int g0   = bb * 128 + gl * 2;
    const int m15  = lane & 15;

    const half8 qA0 = *(const half8*)(qAf + ((size_t)g0 * 64 + lane) * 8);
    const half8 qB0 = *(const half8*)(qBf + ((size_t)g0 * 64 + lane) * 8);
    const half8 qA1 = *(const half8*)(qAf + ((size_t)(g0 + 1) * 64 + lane) * 8);
    const half8 qB1 = *(const half8*)(qBf + ((size_t)(g0 + 1) * 64 + lane) * 8);

    const half8* KP = (const half8*)kfp + (size_t)bb * 128 * 64;
    const half4_t* VT = (const half4_t*)vtf + (size_t)bb * 128 * 64;

    const int nv = nvalid[bb];
    const int nt = (nv + 15) >> 4;
    const int a16 = (lane ^ 16) << 2;
    const int a32 = (lane ^ 32) << 2;

    float m0 = -INFINITY, m1 = -INFINITY;
    floatx4 o0 = {0.f, 0.f, 0.f, 0.f};
    floatx4 o1 = o0;

    int t = w;
    half8 kp;
    half4_t va;
    if (t < nt) {
        kp = KP[t * 64 + lane];
        va = VT[t * 64 + lane];
    }
    for (; t < nt; t += 4) {
        half8 nkp; half4_t nva;
        if (t + 4 < nt) {
            nkp = KP[(t + 4) * 64 + lane];
            nva = VT[(t + 4) * 64 + lane];
        }
        const floatx4 z = {0.f, 0.f, 0.f, 0.f};
        floatx4 s0a = MFMA32F16(kp, qA0, z);
        floatx4 s0b = MFMA32F16(kp, qB0, z);
        floatx4 s1a = MFMA32F16(kp, qA1, z);
        floatx4 s1b = MFMA32F16(kp, qB1, z);
        floatx4 s0 = s0a + s0b;
        floatx4 s1 = s1a + s1b;
        {
            float pm = fmaxf(fmaxf(s0.x, s0.y), fmaxf(s0.z, s0.w));
            pm = fmaxf(pm, bperm(pm, a16));
            pm = fmaxf(pm, bperm(pm, a32));
            half4_t pb;
            if (__all(pm <= m0)) {
                pb[0] = (_Float16)EXP2F(s0.x - m0);
                pb[1] = (_Float16)EXP2F(s0.y - m0);
                pb[2] = (_Float16)EXP2F(s0.z - m0);
                pb[3] = (_Float16)EXP2F(s0.w - m0);
            } else {
                float mnew = fmaxf(m0, pm);
                float corr = EXP2F(m0 - mnew);
                o0.x *= corr; o0.y *= corr; o0.z *= corr; o0.w *= corr;
                pb[0] = (_Float16)EXP2F(s0.x - mnew);
                pb[1] = (_Float16)EXP2F(s0.y - mnew);
                pb[2] = (_Float16)EXP2F(s0.z - mnew);
                pb[3] = (_Float16)EXP2F(s0.w - mnew);
                m0 = mnew;
            }
            o0 = MFMA16F16(va, pb, o0);
        }
        {
            float pm = fmaxf(fmaxf(s1.x, s1.y), fmaxf(s1.z, s1.w));
            pm = fmaxf(pm, bperm(pm, a16));
            pm = fmaxf(pm, bperm(pm, a32));
            half4_t pb;
            if (__all(pm <= m1)) {
                pb[0] = (_Float16)EXP2F(s1.x - m1);
                pb[1] = (_Float16)EXP2F(s1.y - m1);
                pb[2] = (_Float16)EXP2F(s1.z - m1);
                pb[3] = (_Float16)EXP2F(s1.w - m1);
            } else {
                float mnew = fmaxf(m1, pm);
                float corr = EXP2F(m1 - mnew);
                o1.x *= corr; o1.y *= corr; o1.z *= corr; o1.w *= corr;
                pb[0] = (_Float16)EXP2F(s1.x - mnew);
                pb[1] = (_Float16)EXP2F(s1.y - mnew);
                pb[2] = (_Float16)EXP2F(s1.z - mnew);
                pb[3] = (_Float16)EXP2F(s1.w - mnew);
                m1 = mnew;
            }
            o1 = MFMA16F16(va, pb, o1);
        }
        kp = nkp; va = nva;
    }

    cm[(0 * 4 + w) * 64 + lane] = m0;
    cm[(1 * 4 + w) * 64 + lane] = m1;
    co[(0 * 4 + w) * 64 + lane] = o0;
    co[(1 * 4 + w) * 64 + lane] = o1;
    __syncthreads();
    if (w < 2) {
        const int gi = w;
        float gm = -INFINITY;
        #pragma unroll
        for (int w2 = 0; w2 < 4; ++w2) gm = fmaxf(gm, cm[(gi * 4 + w2) * 64 + lane]);
        floatx4 O = {0.f, 0.f, 0.f, 0.f};
        #pragma unroll
        for (int w2 = 0; w2 < 4; ++w2) {
            float f = EXP2F(cm[(gi * 4 + w2) * 64 + lane] - gm);
            floatx4 ow = co[(gi * 4 + w2) * 64 + lane];
            O.x += ow.x * f; O.y += ow.y * f; O.z += ow.z * f; O.w += ow.w * f;
        }
        float L = bperm(O.x, (48 + m15) << 2);
        float inv = 1.0f / L;
        if ((lane >> 4) < 3) {
            float4 ov = make_float4(O.x * inv, O.y * inv, O.z * inv, O.w * inv);
            *(float4*)(out + ((size_t)(g0 + gi) * 16 + m15) * 12 + (lane >> 4) * 4) = ov;
        }
    }
}

extern "C" void kernel_launch(void* const* d_in, const int* in_sizes, int n_in,
                              void* d_out, int out_size, void* d_ws, size_t ws_size,
                              hipStream_t stream) {
    const float* x    = (const float*)d_in[0];
    const int*   mask = (const int*)  d_in[1];
    const float* Wk   = (const float*)d_in[2];   // key_weight
    const float* Wq   = (const float*)d_in[3];   // query_weight
    const float* Wv   = (const float*)d_in[4];   // value_weight
    float* out = (float*)d_out;

    char* base = (char*)d_ws;
    _Float16* qA  = (_Float16*)(base);                    // 1 MB (poison ok)
    _Float16* qB  = (_Float16*)(base + (1u << 20));       // 1 MB (zeroed)
    _Float16* kfp = (_Float16*)(base + (2u << 20));       // 1 MB (zeroed)
    _Float16* vtf = (_Float16*)(base + (3u << 20));       // 0.5 MB (zeroed)
    _Float16* wfh = (_Float16*)(base + 3670016);          // 73728 B
    _Float16* wfl = (_Float16*)(base + 3670016 + 73728);  // 73728 B
    int* dst      = (int*)(base + 3817472);               // 64 KB
    int* nvalid   = (int*)(base + 3817472 + 65536);       // 32 B
    float4* zbase = (float4*)(base + (1u << 20));         // zero [1MB, 3.5MB)

    void* args[] = { (void*)&x, (void*)&mask, (void*)&Wq, (void*)&Wk, (void*)&Wv,
                     (void*)&wfh, (void*)&wfl, (void*)&dst, (void*)&nvalid,
                     (void*)&zbase, (void*)&qA, (void*)&qB, (void*)&kfp,
                     (void*)&vtf, (void*)&out };
    hipError_t err = hipLaunchCooperativeKernel((const void*)fused, dim3(512),
                                                dim3(256), args, 0, stream);
    if (err != hipSuccess) {
        // fallback: proven 3-kernel path
        prep<<<64, 256, 0, stream>>>(Wq, Wk, Wv, mask, wfh, wfl, dst, nvalid, zbase);
        qkv_mfma<<<1024, 256, 0, stream>>>(x, wfh, wfl, dst, qA, qB, kfp, vtf);
        attn<<<512, 256, 0, stream>>>(qA, qB, kfp, vtf, nvalid, out);
    }
}

// Round 4
// 110.619 us; speedup vs baseline: 2.1258x; 2.1258x over previous
//
#include <hip/hip_runtime.h>
#include <math.h>

#define QSCALE (0.2886751345948129f * 1.4426950408889634f)  // 1/sqrt(12) * log2(e)

#if __has_builtin(__builtin_amdgcn_exp2f)
#define EXP2F(x) __builtin_amdgcn_exp2f(x)
#else
#define EXP2F(x) exp2f(x)
#endif

typedef __attribute__((ext_vector_type(8))) _Float16 half8;
typedef __attribute__((ext_vector_type(4))) _Float16 half4_t;
typedef __attribute__((ext_vector_type(4))) float floatx4;

#define MFMA32F16(a, b, c) __builtin_amdgcn_mfma_f32_16x16x32_f16((a), (b), (c), 0, 0, 0)
#define MFMA16F16(a, b, c) __builtin_amdgcn_mfma_f32_16x16x16f16((a), (b), (c), 0, 0, 0)

static __device__ inline float bperm(float v, int addr_bytes) {
    return __int_as_float(__builtin_amdgcn_ds_bpermute(addr_bytes, __float_as_int(v)));
}

// ---------------- Kernel P: prep (wswz | mask_scan) ------------------------
// blocks 0..17: weight swizzle -> fp16 hi/lo B-frags
// blocks 18..25: per-batch mask scan/compaction
// NO zero pass: qkv epilogue writes its own pads; attn masks the last tile.
__global__ __launch_bounds__(256)
void prep(const float* __restrict__ Wq, const float* __restrict__ Wk,
          const float* __restrict__ Wv, const int* __restrict__ mask,
          _Float16* __restrict__ wfh, _Float16* __restrict__ wfl,
          int* __restrict__ dst, int* __restrict__ nvalid)
{
    const int b = blockIdx.x;
    const int tid = threadIdx.x;
    if (b < 18) {
        int t = b * 256 + tid;
        if (t >= 4608) return;             // 24 ks * 3 nt * 64 lanes
        int lane = t & 63;
        int nt   = (t >> 6) % 3;
        int ks   = t / 192;
        const float* W = (nt == 0) ? Wq : (nt == 1) ? Wk : Wv;
        const float scale = (nt == 0) ? QSCALE : 1.0f;
        int col = lane & 15;
        int q8  = lane >> 4;
        half8 hi, lo;
        #pragma unroll
        for (int j = 0; j < 8; ++j) {
            int dim = ks * 32 + q8 * 8 + j;
            float f = (col < 12) ? W[dim * 12 + col] * scale : 0.0f;
            _Float16 h = (_Float16)f;
            hi[j] = h;
            lo[j] = (_Float16)(f - (float)h);
        }
        size_t off = ((size_t)(ks * 3 + nt) * 64 + lane) * 8;
        *(half8*)(wfh + off) = hi;
        *(half8*)(wfl + off) = lo;
    } else {
        __shared__ int cnt[256];
        const int bb = b - 18;
        const int* mb = mask + bb * 2048;
        int local[8]; int c = 0;
        #pragma unroll
        for (int i = 0; i < 8; ++i) { local[i] = (mb[tid * 8 + i] != 0); c += local[i]; }
        cnt[tid] = c;
        __syncthreads();
        for (int off = 1; off < 256; off <<= 1) {
            int u = cnt[tid];
            int add = (tid >= off) ? cnt[tid - off] : 0;
            __syncthreads();
            cnt[tid] = u + add;
            __syncthreads();
        }
        int run = (tid == 0) ? 0 : cnt[tid - 1];
        int* db = dst + bb * 2048;
        #pragma unroll
        for (int i = 0; i < 8; ++i) { db[tid * 8 + i] = local[i] ? run : -1; run += local[i]; }
        if (tid == 255) nvalid[bb] = cnt[255];
    }
}

// ---------------- Kernel 1: QKV projection, fp16-split MFMA ----------------
// grid=1024 (16 rows/block), block=256 (4 waves split K: 6 x 32-dim steps).
// Epilogue packs attention operands AND writes the zero pads previously
// provided by the zero pass:
//   Q -> qA (q_hi dup in K-slots 0..11 & 16..27) + qB (q_lo in 0..11, ZEROS
//        written to 16..27; slots 12..15/28..31 stay poison but multiply
//        kfp zeros)
//   K -> kfp packed A-frag: k_hi slots 0..11, k_lo slots 16..27, ZEROS at
//        12..15 & 28..31 (written by the col 12..15 threads)
//   V^T -> vtf A-frag (fp16) + ones row (l-accumulator); rows 13..15 feed
//        unread C rows (finite poison ok)
__global__ __launch_bounds__(256, 3)
void qkv_mfma(const float* __restrict__ x, const _Float16* __restrict__ wfh,
              const _Float16* __restrict__ wfl, const int* __restrict__ dst,
              _Float16* __restrict__ qA, _Float16* __restrict__ qB,
              _Float16* __restrict__ kfp, _Float16* __restrict__ vtf)
{
    __shared__ __align__(16) float cbuf[3072];   // [w][nt][lane][4]
    const int tid  = threadIdx.x;
    const int lane = tid & 63;
    const int w    = tid >> 6;
    const int g    = blockIdx.x;
    const int rowbase = g * 16;
    const int m15 = lane & 15;
    const int q8  = lane >> 4;

    const float* xbase = x + (size_t)(rowbase + m15) * 768 + q8 * 8;
    const half8* WH = (const half8*)wfh;
    const half8* WL = (const half8*)wfl;

    // issue ALL x loads up front (independent, 12 in flight)
    float xv[6][8];
    #pragma unroll
    for (int s = 0; s < 6; ++s) {
        const int ks = w * 6 + s;
        *(float4*)(xv[s])     = *(const float4*)(xbase + ks * 32);
        *(float4*)(xv[s] + 4) = *(const float4*)(xbase + ks * 32 + 4);
    }

    floatx4 acc0 = {0.f, 0.f, 0.f, 0.f};
    floatx4 acc1 = acc0, acc2 = acc0;

    // weight frags: double-buffered
    half8 bh[2][3], bl[2][3];
    {
        const int ks = w * 6;
        #pragma unroll
        for (int n = 0; n < 3; ++n) {
            bh[0][n] = WH[(ks * 3 + n) * 64 + lane];
            bl[0][n] = WL[(ks * 3 + n) * 64 + lane];
        }
    }

    #pragma unroll
    for (int s = 0; s < 6; ++s) {
        const int cur = s & 1, nxt = cur ^ 1;
        if (s < 5) {
            const int ksn = w * 6 + s + 1;
            #pragma unroll
            for (int n = 0; n < 3; ++n) {
                bh[nxt][n] = WH[(ksn * 3 + n) * 64 + lane];
                bl[nxt][n] = WL[(ksn * 3 + n) * 64 + lane];
            }
        }
        half8 ah, al;
        #pragma unroll
        for (int j = 0; j < 8; ++j) {
            _Float16 h = (_Float16)xv[s][j];
            ah[j] = h;
            al[j] = (_Float16)(xv[s][j] - (float)h);
        }
        acc0 = MFMA32F16(ah, bh[cur][0], acc0);
        acc1 = MFMA32F16(ah, bh[cur][1], acc1);
        acc2 = MFMA32F16(ah, bh[cur][2], acc2);
        acc0 = MFMA32F16(al, bh[cur][0], acc0);
        acc1 = MFMA32F16(al, bh[cur][1], acc1);
        acc2 = MFMA32F16(al, bh[cur][2], acc2);
        acc0 = MFMA32F16(ah, bl[cur][0], acc0);
        acc1 = MFMA32F16(ah, bl[cur][1], acc1);
        acc2 = MFMA32F16(ah, bl[cur][2], acc2);
    }

    *(floatx4*)(cbuf + ((w * 3 + 0) * 64 + lane) * 4) = acc0;
    *(floatx4*)(cbuf + ((w * 3 + 1) * 64 + lane) * 4) = acc1;
    *(floatx4*)(cbuf + ((w * 3 + 2) * 64 + lane) * 4) = acc2;
    __syncthreads();
    if (w < 3) {
        floatx4 t0 = *(const floatx4*)(cbuf + ((0 * 3 + w) * 64 + lane) * 4);
        floatx4 t1 = *(const floatx4*)(cbuf + ((1 * 3 + w) * 64 + lane) * 4);
        floatx4 t2 = *(const floatx4*)(cbuf + ((2 * 3 + w) * 64 + lane) * 4);
        floatx4 t3 = *(const floatx4*)(cbuf + ((3 * 3 + w) * 64 + lane) * 4);
        floatx4 tot = t0 + t1 + t2 + t3;
        const int col = m15;
        const int r0  = q8 * 4;
        #pragma unroll
        for (int r = 0; r < 4; ++r) {
            const int row = rowbase + r0 + r;
            const float val = tot[r];
            if (w == 0) {                  // Q -> qA (hi dup) + qB (lo + zero pad)
                if (col < 12) {
                    size_t fb = (size_t)g * 64;
                    size_t offL = (fb + (col >> 3) * 16 + (r0 + r)) * 8 + (col & 7);
                    size_t offH = (fb + (2 + (col >> 3)) * 16 + (r0 + r)) * 8 + (col & 7);
                    _Float16 h = (_Float16)val;
                    qA[offL] = h;
                    qA[offH] = h;          // duplicate hi into K-slots 16..27
                    qB[offL] = (_Float16)(val - (float)h);
                    qB[offH] = (_Float16)0.0f;   // zero K-slots 16..27 (was zbase)
                }
            } else {
                const int d = dst[row];
                if (d >= 0) {
                    const int bb = row >> 11;
                    if (w == 1) {          // K -> packed hi|lo A-frag (compacted)
                        size_t fb = ((size_t)(bb * 128 + (d >> 4))) * 64;
                        size_t offH = (fb + (col >> 3) * 16 + (d & 15)) * 8 + (col & 7);
                        size_t offL = (fb + (2 + (col >> 3)) * 16 + (d & 15)) * 8 + (col & 7);
                        if (col < 12) {
                            _Float16 h = (_Float16)val;
                            kfp[offH] = h;
                            kfp[offL] = (_Float16)(val - (float)h);
                        } else {           // col 12..15: zero pads at slots 12..15 / 28..31
                            kfp[offH] = (_Float16)0.0f;
                            kfp[offL] = (_Float16)0.0f;
                        }
                    } else {               // V^T -> A-frag layout (fp16), + ones row
                        if (col < 12) {
                            size_t off = (((size_t)(bb * 128 + (d >> 4))) * 64
                                          + ((d & 15) >> 2) * 16 + col) * 4 + (d & 3);
                            vtf[off] = (_Float16)val;
                        } else if (col == 12) {   // l-accumulator ones row
                            size_t off = (((size_t)(bb * 128 + (d >> 4))) * 64
                                          + ((d & 15) >> 2) * 16 + 12) * 4 + (d & 3);
                            vtf[off] = (_Float16)1.0f;
                        }
                    }
                }
            }
        }
    }
}

// ---------------- Kernel 2: MFMA flash attention ---------------------------
// grid=512 (two 16-row q-groups per block), block=256 (4 waves stride-4 over
// 16-key tiles). XCD swizzle: batch = blockIdx&7 pins each batch's blocks to
// one XCD. Packed-K trick: head dim 12 <= 16, so k_lo lives in K-slots
// 16..27 of the SAME A-frag; two independent MFMAs per group give all three
// fp16-split terms. Last-tile invalid keys (d >= nv) are zeroed in-register
// (replaces the old buffer zero pass; identical math: score 0, V 0, ones 0).
__global__ __launch_bounds__(256)
void attn(const _Float16* __restrict__ qAf, const _Float16* __restrict__ qBf,
          const _Float16* __restrict__ kfp, const _Float16* __restrict__ vtf,
          const int* __restrict__ nvalid, float* __restrict__ out)
{
    __shared__ float cm[512];
    __shared__ __align__(16) floatx4 co[512];
    const int tid  = threadIdx.x;
    const int lane = tid & 63;
    const int w    = tid >> 6;
    const int bb   = blockIdx.x & 7;       // XCD-pinned batch
    const int gl   = blockIdx.x >> 3;      // 0..63 within batch
    const int g0   = bb * 128 + gl * 2;    // first q-group
    const int m15  = lane & 15;

    const half8 qA0 = *(const half8*)(qAf + ((size_t)g0 * 64 + lane) * 8);
    const half8 qB0 = *(const half8*)(qBf + ((size_t)g0 * 64 + lane) * 8);
    const half8 qA1 = *(const half8*)(qAf + ((size_t)(g0 + 1) * 64 + lane) * 8);
    const half8 qB1 = *(const half8*)(qBf + ((size_t)(g0 + 1) * 64 + lane) * 8);

    const half8* KP = (const half8*)kfp + (size_t)bb * 128 * 64;
    const half4_t* VT = (const half4_t*)vtf + (size_t)bb * 128 * 64;

    const int nv = nvalid[bb];
    const int nt = (nv + 15) >> 4;         // 16-key tiles (<=128)
    const int a16 = (lane ^ 16) << 2;
    const int a32 = (lane ^ 32) << 2;

    float m0 = -INFINITY, m1 = -INFINITY;
    floatx4 o0 = {0.f, 0.f, 0.f, 0.f};
    floatx4 o1 = o0;

    int t = w;
    half8 kp;
    half4_t va;
    if (t < nt) {
        kp = KP[t * 64 + lane];
        va = VT[t * 64 + lane];
    }
    for (; t < nt; t += 4) {
        half8 nkp; half4_t nva;
        if (t + 4 < nt) {
            nkp = KP[(t + 4) * 64 + lane];
            nva = VT[(t + 4) * 64 + lane];
        }
        if (t == nt - 1) {                 // mask invalid keys of the last tile
            const int kb = t * 16;
            if (kb + m15 >= nv) {          // kp key index = t*16 + (lane&15)
                #pragma unroll
                for (int j = 0; j < 8; ++j) kp[j] = (_Float16)0.0f;
            }
            const int kv = kb + (lane >> 4) * 4;  // va key index = kv + j
            #pragma unroll
            for (int j = 0; j < 4; ++j)
                if (kv + j >= nv) va[j] = (_Float16)0.0f;
        }
        const floatx4 z = {0.f, 0.f, 0.f, 0.f};
        floatx4 s0a = MFMA32F16(kp, qA0, z);   // kh*qh + kl*qh
        floatx4 s0b = MFMA32F16(kp, qB0, z);   // kh*ql
        floatx4 s1a = MFMA32F16(kp, qA1, z);
        floatx4 s1b = MFMA32F16(kp, qB1, z);
        floatx4 s0 = s0a + s0b;
        floatx4 s1 = s1a + s1b;
        // group 0 softmax step
        {
            float pm = fmaxf(fmaxf(s0.x, s0.y), fmaxf(s0.z, s0.w));
            pm = fmaxf(pm, bperm(pm, a16));
            pm = fmaxf(pm, bperm(pm, a32));
            half4_t pb;
            if (__all(pm <= m0)) {             // defer: mnew == m0 exactly
                pb[0] = (_Float16)EXP2F(s0.x - m0);
                pb[1] = (_Float16)EXP2F(s0.y - m0);
                pb[2] = (_Float16)EXP2F(s0.z - m0);
                pb[3] = (_Float16)EXP2F(s0.w - m0);
            } else {
                float mnew = fmaxf(m0, pm);
                float corr = EXP2F(m0 - mnew);
                o0.x *= corr; o0.y *= corr; o0.z *= corr; o0.w *= corr;
                pb[0] = (_Float16)EXP2F(s0.x - mnew);
                pb[1] = (_Float16)EXP2F(s0.y - mnew);
                pb[2] = (_Float16)EXP2F(s0.z - mnew);
                pb[3] = (_Float16)EXP2F(s0.w - mnew);
                m0 = mnew;
            }
            o0 = MFMA16F16(va, pb, o0);
        }
        // group 1 softmax step
        {
            float pm = fmaxf(fmaxf(s1.x, s1.y), fmaxf(s1.z, s1.w));
            pm = fmaxf(pm, bperm(pm, a16));
            pm = fmaxf(pm, bperm(pm, a32));
            half4_t pb;
            if (__all(pm <= m1)) {
                pb[0] = (_Float16)EXP2F(s1.x - m1);
                pb[1] = (_Float16)EXP2F(s1.y - m1);
                pb[2] = (_Float16)EXP2F(s1.z - m1);
                pb[3] = (_Float16)EXP2F(s1.w - m1);
            } else {
                float mnew = fmaxf(m1, pm);
                float corr = EXP2F(m1 - mnew);
                o1.x *= corr; o1.y *= corr; o1.z *= corr; o1.w *= corr;
                pb[0] = (_Float16)EXP2F(s1.x - mnew);
                pb[1] = (_Float16)EXP2F(s1.y - mnew);
                pb[2] = (_Float16)EXP2F(s1.z - mnew);
                pb[3] = (_Float16)EXP2F(s1.w - mnew);
                m1 = mnew;
            }
            o1 = MFMA16F16(va, pb, o1);
        }
        kp = nkp; va = nva;
    }

    // ---- 4-way combine per group ----
    cm[(0 * 4 + w) * 64 + lane] = m0;
    cm[(1 * 4 + w) * 64 + lane] = m1;
    co[(0 * 4 + w) * 64 + lane] = o0;
    co[(1 * 4 + w) * 64 + lane] = o1;
    __syncthreads();
    if (w < 2) {
        const int gi = w;
        float gm = -INFINITY;
        #pragma unroll
        for (int w2 = 0; w2 < 4; ++w2) gm = fmaxf(gm, cm[(gi * 4 + w2) * 64 + lane]);
        floatx4 O = {0.f, 0.f, 0.f, 0.f};
        #pragma unroll
        for (int w2 = 0; w2 < 4; ++w2) {
            float f = EXP2F(cm[(gi * 4 + w2) * 64 + lane] - gm);
            floatx4 ow = co[(gi * 4 + w2) * 64 + lane];
            O.x += ow.x * f; O.y += ow.y * f; O.z += ow.z * f; O.w += ow.w * f;
        }
        float L = bperm(O.x, (48 + m15) << 2);   // l at C row 12
        float inv = 1.0f / L;
        if ((lane >> 4) < 3) {
            float4 ov = make_float4(O.x * inv, O.y * inv, O.z * inv, O.w * inv);
            *(float4*)(out + ((size_t)(g0 + gi) * 16 + m15) * 12 + (lane >> 4) * 4) = ov;
        }
    }
}

extern "C" void kernel_launch(void* const* d_in, const int* in_sizes, int n_in,
                              void* d_out, int out_size, void* d_ws, size_t ws_size,
                              hipStream_t stream) {
    const float* x    = (const float*)d_in[0];
    const int*   mask = (const int*)  d_in[1];
    const float* Wk   = (const float*)d_in[2];   // key_weight
    const float* Wq   = (const float*)d_in[3];   // query_weight
    const float* Wv   = (const float*)d_in[4];   // value_weight
    float* out = (float*)d_out;

    char* base = (char*)d_ws;
    _Float16* qA  = (_Float16*)(base);                    // 1 MB (poison ok)
    _Float16* qB  = (_Float16*)(base + (1u << 20));       // 1 MB (pads written by qkv)
    _Float16* kfp = (_Float16*)(base + (2u << 20));       // 1 MB (pads written by qkv)
    _Float16* vtf = (_Float16*)(base + (3u << 20));       // 0.5 MB (poison rows unread)
    _Float16* wfh = (_Float16*)(base + 3670016);          // 73728 B
    _Float16* wfl = (_Float16*)(base + 3670016 + 73728);  // 73728 B
    int* dst      = (int*)(base + 3817472);               // 64 KB
    int* nvalid   = (int*)(base + 3817472 + 65536);       // 32 B

    prep<<<26, 256, 0, stream>>>(Wq, Wk, Wv, mask, wfh, wfl, dst, nvalid);
    qkv_mfma<<<1024, 256, 0, stream>>>(x, wfh, wfl, dst, qA, qB, kfp, vtf);
    attn<<<512, 256, 0, stream>>>(qA, qB, kfp, vtf, nvalid, out);
}

// Round 5
// 108.016 us; speedup vs baseline: 2.1770x; 1.0241x over previous
//
#include <hip/hip_runtime.h>
#include <math.h>

#define QSCALE (0.2886751345948129f * 1.4426950408889634f)  // 1/sqrt(12) * log2(e)

#if __has_builtin(__builtin_amdgcn_exp2f)
#define EXP2F(x) __builtin_amdgcn_exp2f(x)
#else
#define EXP2F(x) exp2f(x)
#endif

typedef __attribute__((ext_vector_type(8))) _Float16 half8;
typedef __attribute__((ext_vector_type(4))) _Float16 half4_t;
typedef __attribute__((ext_vector_type(4))) float floatx4;

#define MFMA32F16(a, b, c) __builtin_amdgcn_mfma_f32_16x16x32_f16((a), (b), (c), 0, 0, 0)
#define MFMA16F16(a, b, c) __builtin_amdgcn_mfma_f32_16x16x16f16((a), (b), (c), 0, 0, 0)

static __device__ inline float bperm(float v, int addr_bytes) {
    return __int_as_float(__builtin_amdgcn_ds_bpermute(addr_bytes, __float_as_int(v)));
}

// ---------------- Kernel P: prep (wswz | mask_scan) ------------------------
// blocks 0..17: weight swizzle -> fp16 hi/lo B-frags
// blocks 18..25: per-batch mask scan/compaction
// NO zero pass: qkv epilogue writes its own pads; attn masks the last tile.
__global__ __launch_bounds__(256)
void prep(const float* __restrict__ Wq, const float* __restrict__ Wk,
          const float* __restrict__ Wv, const int* __restrict__ mask,
          _Float16* __restrict__ wfh, _Float16* __restrict__ wfl,
          int* __restrict__ dst, int* __restrict__ nvalid)
{
    const int b = blockIdx.x;
    const int tid = threadIdx.x;
    if (b < 18) {
        int t = b * 256 + tid;
        if (t >= 4608) return;             // 24 ks * 3 nt * 64 lanes
        int lane = t & 63;
        int nt   = (t >> 6) % 3;
        int ks   = t / 192;
        const float* W = (nt == 0) ? Wq : (nt == 1) ? Wk : Wv;
        const float scale = (nt == 0) ? QSCALE : 1.0f;
        int col = lane & 15;
        int q8  = lane >> 4;
        half8 hi, lo;
        #pragma unroll
        for (int j = 0; j < 8; ++j) {
            int dim = ks * 32 + q8 * 8 + j;
            float f = (col < 12) ? W[dim * 12 + col] * scale : 0.0f;
            _Float16 h = (_Float16)f;
            hi[j] = h;
            lo[j] = (_Float16)(f - (float)h);
        }
        size_t off = ((size_t)(ks * 3 + nt) * 64 + lane) * 8;
        *(half8*)(wfh + off) = hi;
        *(half8*)(wfl + off) = lo;
    } else {
        __shared__ int cnt[256];
        const int bb = b - 18;
        const int* mb = mask + bb * 2048;
        int local[8]; int c = 0;
        #pragma unroll
        for (int i = 0; i < 8; ++i) { local[i] = (mb[tid * 8 + i] != 0); c += local[i]; }
        cnt[tid] = c;
        __syncthreads();
        for (int off = 1; off < 256; off <<= 1) {
            int u = cnt[tid];
            int add = (tid >= off) ? cnt[tid - off] : 0;
            __syncthreads();
            cnt[tid] = u + add;
            __syncthreads();
        }
        int run = (tid == 0) ? 0 : cnt[tid - 1];
        int* db = dst + bb * 2048;
        #pragma unroll
        for (int i = 0; i < 8; ++i) { db[tid * 8 + i] = local[i] ? run : -1; run += local[i]; }
        if (tid == 255) nvalid[bb] = cnt[255];
    }
}

// ---------------- Kernel 1: QKV projection, fp16-split MFMA ----------------
// grid=1024 (16 rows/block), block=256 (4 waves split K: 6 x 32-dim steps).
// Epilogue packs attention operands AND writes the zero pads:
//   Q -> qA (q_hi dup in K-slots 0..11 & 16..27) + qB (q_lo in 0..11, zeros
//        at 16..27)
//   K -> kfp packed A-frag: k_hi slots 0..11, k_lo slots 16..27, zeros at
//        12..15 & 28..31 (written by the col 12..15 threads)
//   V^T -> vtf A-frag (fp16) + ones row (l-accumulator)
__global__ __launch_bounds__(256, 3)
void qkv_mfma(const float* __restrict__ x, const _Float16* __restrict__ wfh,
              const _Float16* __restrict__ wfl, const int* __restrict__ dst,
              _Float16* __restrict__ qA, _Float16* __restrict__ qB,
              _Float16* __restrict__ kfp, _Float16* __restrict__ vtf)
{
    __shared__ __align__(16) float cbuf[3072];   // [w][nt][lane][4]
    const int tid  = threadIdx.x;
    const int lane = tid & 63;
    const int w    = tid >> 6;
    const int g    = blockIdx.x;
    const int rowbase = g * 16;
    const int m15 = lane & 15;
    const int q8  = lane >> 4;

    const float* xbase = x + (size_t)(rowbase + m15) * 768 + q8 * 8;
    const half8* WH = (const half8*)wfh;
    const half8* WL = (const half8*)wfl;

    // issue ALL x loads up front (independent, 12 in flight)
    float xv[6][8];
    #pragma unroll
    for (int s = 0; s < 6; ++s) {
        const int ks = w * 6 + s;
        *(float4*)(xv[s])     = *(const float4*)(xbase + ks * 32);
        *(float4*)(xv[s] + 4) = *(const float4*)(xbase + ks * 32 + 4);
    }

    floatx4 acc0 = {0.f, 0.f, 0.f, 0.f};
    floatx4 acc1 = acc0, acc2 = acc0;

    // weight frags: double-buffered
    half8 bh[2][3], bl[2][3];
    {
        const int ks = w * 6;
        #pragma unroll
        for (int n = 0; n < 3; ++n) {
            bh[0][n] = WH[(ks * 3 + n) * 64 + lane];
            bl[0][n] = WL[(ks * 3 + n) * 64 + lane];
        }
    }

    #pragma unroll
    for (int s = 0; s < 6; ++s) {
        const int cur = s & 1, nxt = cur ^ 1;
        if (s < 5) {
            const int ksn = w * 6 + s + 1;
            #pragma unroll
            for (int n = 0; n < 3; ++n) {
                bh[nxt][n] = WH[(ksn * 3 + n) * 64 + lane];
                bl[nxt][n] = WL[(ksn * 3 + n) * 64 + lane];
            }
        }
        half8 ah, al;
        #pragma unroll
        for (int j = 0; j < 8; ++j) {
            _Float16 h = (_Float16)xv[s][j];
            ah[j] = h;
            al[j] = (_Float16)(xv[s][j] - (float)h);
        }
        acc0 = MFMA32F16(ah, bh[cur][0], acc0);
        acc1 = MFMA32F16(ah, bh[cur][1], acc1);
        acc2 = MFMA32F16(ah, bh[cur][2], acc2);
        acc0 = MFMA32F16(al, bh[cur][0], acc0);
        acc1 = MFMA32F16(al, bh[cur][1], acc1);
        acc2 = MFMA32F16(al, bh[cur][2], acc2);
        acc0 = MFMA32F16(ah, bl[cur][0], acc0);
        acc1 = MFMA32F16(ah, bl[cur][1], acc1);
        acc2 = MFMA32F16(ah, bl[cur][2], acc2);
    }

    *(floatx4*)(cbuf + ((w * 3 + 0) * 64 + lane) * 4) = acc0;
    *(floatx4*)(cbuf + ((w * 3 + 1) * 64 + lane) * 4) = acc1;
    *(floatx4*)(cbuf + ((w * 3 + 2) * 64 + lane) * 4) = acc2;
    __syncthreads();
    if (w < 3) {
        floatx4 t0 = *(const floatx4*)(cbuf + ((0 * 3 + w) * 64 + lane) * 4);
        floatx4 t1 = *(const floatx4*)(cbuf + ((1 * 3 + w) * 64 + lane) * 4);
        floatx4 t2 = *(const floatx4*)(cbuf + ((2 * 3 + w) * 64 + lane) * 4);
        floatx4 t3 = *(const floatx4*)(cbuf + ((3 * 3 + w) * 64 + lane) * 4);
        floatx4 tot = t0 + t1 + t2 + t3;
        const int col = m15;
        const int r0  = q8 * 4;
        #pragma unroll
        for (int r = 0; r < 4; ++r) {
            const int row = rowbase + r0 + r;
            const float val = tot[r];
            if (w == 0) {                  // Q -> qA (hi dup) + qB (lo + zero pad)
                if (col < 12) {
                    size_t fb = (size_t)g * 64;
                    size_t offL = (fb + (col >> 3) * 16 + (r0 + r)) * 8 + (col & 7);
                    size_t offH = (fb + (2 + (col >> 3)) * 16 + (r0 + r)) * 8 + (col & 7);
                    _Float16 h = (_Float16)val;
                    qA[offL] = h;
                    qA[offH] = h;          // duplicate hi into K-slots 16..27
                    qB[offL] = (_Float16)(val - (float)h);
                    qB[offH] = (_Float16)0.0f;   // zero K-slots 16..27
                }
            } else {
                const int d = dst[row];
                if (d >= 0) {
                    const int bb = row >> 11;
                    if (w == 1) {          // K -> packed hi|lo A-frag (compacted)
                        size_t fb = ((size_t)(bb * 128 + (d >> 4))) * 64;
                        size_t offH = (fb + (col >> 3) * 16 + (d & 15)) * 8 + (col & 7);
                        size_t offL = (fb + (2 + (col >> 3)) * 16 + (d & 15)) * 8 + (col & 7);
                        if (col < 12) {
                            _Float16 h = (_Float16)val;
                            kfp[offH] = h;
                            kfp[offL] = (_Float16)(val - (float)h);
                        } else {           // col 12..15: zero pads at slots 12..15 / 28..31
                            kfp[offH] = (_Float16)0.0f;
                            kfp[offL] = (_Float16)0.0f;
                        }
                    } else {               // V^T -> A-frag layout (fp16), + ones row
                        if (col < 12) {
                            size_t off = (((size_t)(bb * 128 + (d >> 4))) * 64
                                          + ((d & 15) >> 2) * 16 + col) * 4 + (d & 3);
                            vtf[off] = (_Float16)val;
                        } else if (col == 12) {   // l-accumulator ones row
                            size_t off = (((size_t)(bb * 128 + (d >> 4))) * 64
                                          + ((d & 15) >> 2) * 16 + 12) * 4 + (d & 3);
                            vtf[off] = (_Float16)1.0f;
                        }
                    }
                }
            }
        }
    }
}

// ---------------- Kernel 2: MFMA flash attention ---------------------------
// grid=1024 (ONE 16-row q-group per block), block=256 (4 waves stride-4 over
// 16-key tiles). TLP change vs prior round: two q-groups per block -> one
// group in each of two blocks. Same math/order per group (bit-identical
// output); doubles blocks/CU (2->4) so bperm/exp stalls overlap across waves.
// XCD swizzle: batch = blockIdx&7 pins each batch's blocks to one XCD.
// Packed-K trick: k_hi slots 0..11, k_lo slots 16..27 of one A-frag; two
// MFMAs give all three fp16-split terms. Last-tile invalid keys zeroed
// in-register.
__global__ __launch_bounds__(256)
void attn(const _Float16* __restrict__ qAf, const _Float16* __restrict__ qBf,
          const _Float16* __restrict__ kfp, const _Float16* __restrict__ vtf,
          const int* __restrict__ nvalid, float* __restrict__ out)
{
    __shared__ float cm[256];
    __shared__ __align__(16) floatx4 co[256];
    const int tid  = threadIdx.x;
    const int lane = tid & 63;
    const int w    = tid >> 6;
    const int bb   = blockIdx.x & 7;       // XCD-pinned batch
    const int gl   = blockIdx.x >> 3;      // 0..127 within batch
    const int g0   = bb * 128 + gl;        // q-group
    const int m15  = lane & 15;

    const half8 qA0 = *(const half8*)(qAf + ((size_t)g0 * 64 + lane) * 8);
    const half8 qB0 = *(const half8*)(qBf + ((size_t)g0 * 64 + lane) * 8);

    const half8* KP = (const half8*)kfp + (size_t)bb * 128 * 64;
    const half4_t* VT = (const half4_t*)vtf + (size_t)bb * 128 * 64;

    const int nv = nvalid[bb];
    const int nt = (nv + 15) >> 4;         // 16-key tiles (<=128)
    const int a16 = (lane ^ 16) << 2;
    const int a32 = (lane ^ 32) << 2;

    float m0 = -INFINITY;
    floatx4 o0 = {0.f, 0.f, 0.f, 0.f};

    int t = w;
    half8 kp;
    half4_t va;
    if (t < nt) {
        kp = KP[t * 64 + lane];
        va = VT[t * 64 + lane];
    }
    for (; t < nt; t += 4) {
        half8 nkp; half4_t nva;
        if (t + 4 < nt) {
            nkp = KP[(t + 4) * 64 + lane];
            nva = VT[(t + 4) * 64 + lane];
        }
        if (t == nt - 1) {                 // mask invalid keys of the last tile
            const int kb = t * 16;
            if (kb + m15 >= nv) {          // kp key index = t*16 + (lane&15)
                #pragma unroll
                for (int j = 0; j < 8; ++j) kp[j] = (_Float16)0.0f;
            }
            const int kv = kb + (lane >> 4) * 4;  // va key index = kv + j
            #pragma unroll
            for (int j = 0; j < 4; ++j)
                if (kv + j >= nv) va[j] = (_Float16)0.0f;
        }
        const floatx4 z = {0.f, 0.f, 0.f, 0.f};
        floatx4 s0a = MFMA32F16(kp, qA0, z);   // kh*qh + kl*qh
        floatx4 s0b = MFMA32F16(kp, qB0, z);   // kh*ql
        floatx4 s0 = s0a + s0b;
        {
            float pm = fmaxf(fmaxf(s0.x, s0.y), fmaxf(s0.z, s0.w));
            pm = fmaxf(pm, bperm(pm, a16));
            pm = fmaxf(pm, bperm(pm, a32));
            half4_t pb;
            if (__all(pm <= m0)) {             // defer: mnew == m0 exactly
                pb[0] = (_Float16)EXP2F(s0.x - m0);
                pb[1] = (_Float16)EXP2F(s0.y - m0);
                pb[2] = (_Float16)EXP2F(s0.z - m0);
                pb[3] = (_Float16)EXP2F(s0.w - m0);
            } else {
                float mnew = fmaxf(m0, pm);
                float corr = EXP2F(m0 - mnew);
                o0.x *= corr; o0.y *= corr; o0.z *= corr; o0.w *= corr;
                pb[0] = (_Float16)EXP2F(s0.x - mnew);
                pb[1] = (_Float16)EXP2F(s0.y - mnew);
                pb[2] = (_Float16)EXP2F(s0.z - mnew);
                pb[3] = (_Float16)EXP2F(s0.w - mnew);
                m0 = mnew;
            }
            o0 = MFMA16F16(va, pb, o0);
        }
        kp = nkp; va = nva;
    }

    // ---- 4-way combine ----
    cm[w * 64 + lane] = m0;
    co[w * 64 + lane] = o0;
    __syncthreads();
    if (w == 0) {
        float gm = -INFINITY;
        #pragma unroll
        for (int w2 = 0; w2 < 4; ++w2) gm = fmaxf(gm, cm[w2 * 64 + lane]);
        floatx4 O = {0.f, 0.f, 0.f, 0.f};
        #pragma unroll
        for (int w2 = 0; w2 < 4; ++w2) {
            float f = EXP2F(cm[w2 * 64 + lane] - gm);
            floatx4 ow = co[w2 * 64 + lane];
            O.x += ow.x * f; O.y += ow.y * f; O.z += ow.z * f; O.w += ow.w * f;
        }
        float L = bperm(O.x, (48 + m15) << 2);   // l at C row 12
        float inv = 1.0f / L;
        if ((lane >> 4) < 3) {
            float4 ov = make_float4(O.x * inv, O.y * inv, O.z * inv, O.w * inv);
            *(float4*)(out + ((size_t)g0 * 16 + m15) * 12 + (lane >> 4) * 4) = ov;
        }
    }
}

extern "C" void kernel_launch(void* const* d_in, const int* in_sizes, int n_in,
                              void* d_out, int out_size, void* d_ws, size_t ws_size,
                              hipStream_t stream) {
    const float* x    = (const float*)d_in[0];
    const int*   mask = (const int*)  d_in[1];
    const float* Wk   = (const float*)d_in[2];   // key_weight
    const float* Wq   = (const float*)d_in[3];   // query_weight
    const float* Wv   = (const float*)d_in[4];   // value_weight
    float* out = (float*)d_out;

    char* base = (char*)d_ws;
    _Float16* qA  = (_Float16*)(base);                    // 1 MB (poison ok)
    _Float16* qB  = (_Float16*)(base + (1u << 20));       // 1 MB (pads written by qkv)
    _Float16* kfp = (_Float16*)(base + (2u << 20));       // 1 MB (pads written by qkv)
    _Float16* vtf = (_Float16*)(base + (3u << 20));       // 0.5 MB (poison rows unread)
    _Float16* wfh = (_Float16*)(base + 3670016);          // 73728 B
    _Float16* wfl = (_Float16*)(base + 3670016 + 73728);  // 73728 B
    int* dst      = (int*)(base + 3817472);               // 64 KB
    int* nvalid   = (int*)(base + 3817472 + 65536);       // 32 B

    prep<<<26, 256, 0, stream>>>(Wq, Wk, Wv, mask, wfh, wfl, dst, nvalid);
    qkv_mfma<<<1024, 256, 0, stream>>>(x, wfh, wfl, dst, qA, qB, kfp, vtf);
    attn<<<1024, 256, 0, stream>>>(qA, qB, kfp, vtf, nvalid, out);
}